// Round 8
// baseline (325.852 us; speedup 1.0000x reference)
//
#include <hip/hip_runtime.h>

#define N 4096
#define NT 1024
#define BATCH 64
#define KCAND 8
#define IOU_THR 0.55f
#define INF 0x7fffffff
#define NBINS 14
#define NBKT 42     // 3 classes * 14 x-bins of 256px
#define BCAP 320

__device__ float4 g_wsum[N];   // weighted sums; always written before read per launch

__device__ __forceinline__ float rl_f(float v, int lane) {
  return __int_as_float(__builtin_amdgcn_readlane(__float_as_int(v), lane));
}
__device__ __forceinline__ int rl_i(int v, int lane) {
  return __builtin_amdgcn_readlane(v, lane);
}

__global__ __launch_bounds__(NT) void wbf_kernel(
    const float* __restrict__ boxes,   // [16,256,6]
    const float* __restrict__ offs,    // [16,2]
    float* __restrict__ out)           // [1000,6]
{
  // ---- LDS ~137.7 KB (limit 160 KB) ----
  __shared__ float4 s_mbox[N];                   // 64 KB (sort keys alias later)
  __shared__ float  s_ssum[N];                   // 16 KB
  __shared__ unsigned short s_cc[N];             //  8 KB  cnt | cls<<14
  __shared__ unsigned s_gate32[N];               // 16 KB  (int)m.x<<16 | (int)m.y
  __shared__ unsigned short s_bkt[NBKT][BCAP];   // 26.25 KB cluster-index buckets
  __shared__ int s_bktlen[NBKT];
  __shared__ uint4 s_cand4[BATCH];               // 8 x u16 candidates per box
  __shared__ int   s_ccnt[BATCH];
  __shared__ __align__(16) float s_batch[BATCH][8];  // 2 KB (padded rows)
  __shared__ unsigned s_bgate[BATCH];            // (cls<<12|x)<<16 | y  (phase 1.5)
  __shared__ unsigned long long s_pm[BATCH];
  __shared__ int s_min[2];
  __shared__ int s_num, s_resume, s_ovf;

  const int tid = threadIdx.x;

  if (tid < NBKT) s_bktlen[tid] = 0;
  if (tid == 0) { s_num = 0; s_resume = BATCH; s_ovf = 0; s_min[0] = INF; s_min[1] = INF; }

  // ================= batched WBF scan =================
  for (int t0 = 0; t0 < N; t0 += BATCH) {
    // ---- stage batch boxes (fused gate build); clear counters/masks ----
    if (tid < BATCH) {
      int gi = t0 + tid;
      const float* br = boxes + (size_t)gi * 6;
      int p = gi >> 8;
      float ox = offs[2 * p], oy = offs[2 * p + 1];
      float x1 = br[0] + ox, y1 = br[1] + oy;
      float x2 = br[2] + ox, y2 = br[3] + oy;
      float sc = br[4], lb = br[5];
      s_batch[tid][0] = x1; s_batch[tid][1] = y1;
      s_batch[tid][2] = x2; s_batch[tid][3] = y2;
      s_batch[tid][4] = sc; s_batch[tid][5] = lb;
      s_bgate[tid] = ((unsigned)(((int)lb << 12) | (int)x1) << 16) | (unsigned)(int)y1;
    } else if (tid < 2 * BATCH) {
      s_ccnt[tid - BATCH] = 0;
    } else if (tid < 3 * BATCH) {
      s_pm[tid - 2 * BATCH] = 0ull;
    }
    __syncthreads();

    int nm0 = s_num;
    int use_linear = s_ovf;

    // ---- phase 1: candidates vs clean pre-batch clusters (bucketed + gate32) ----
    if (!use_linear) {
      int b = tid >> 4, sl = tid & 15;        // 16 threads per box
      float qx1 = s_batch[b][0], qy1 = s_batch[b][1];
      float qx2 = s_batch[b][2], qy2 = s_batch[b][3];
      int cls = (int)s_batch[b][5];
      unsigned qxq = (unsigned)(int)qx1, qyq = (unsigned)(int)qy1;
      float aA = (qx2 - qx1) * (qy2 - qy1);
      int bb = ((int)qx1) >> 8;
      int jlo = bb > 0 ? bb - 1 : 0;
      int jhi = bb < NBINS - 1 ? bb + 1 : NBINS - 1;
      for (int j = jlo; j <= jhi; ++j) {
        int bk = cls * NBINS + j;
        int len = s_bktlen[bk]; if (len > BCAP) len = BCAP;
        for (int e = sl; e < len; e += 16) {
          int c = (int)s_bkt[bk][e];
          unsigned g = s_gate32[c];
          unsigned dx = __usad(g >> 16, qxq, 0u);
          unsigned dy = __usad(g & 0xFFFFu, qyq, 0u);
          if (dx <= 60u && dy <= 60u) {
            float4 m = s_mbox[c];
            float xx1 = fmaxf(m.x, qx1), yy1 = fmaxf(m.y, qy1);
            float xx2 = fminf(m.z, qx2), yy2 = fminf(m.w, qy2);
            float iw = fmaxf(xx2 - xx1, 0.0f), ih = fmaxf(yy2 - yy1, 0.0f);
            float inter = iw * ih;
            float aB = (m.z - m.x) * (m.w - m.y);
            float uni = aA + aB - inter;
            if (uni > 0.0f && inter / uni > IOU_THR) {
              int pos = atomicAdd(&s_ccnt[b], 1);
              if (pos < KCAND) ((unsigned short*)&s_cand4[b])[pos] = (unsigned short)c;
            }
          }
        }
      }
    } else {
      // exact linear fallback (bucket overflow happened earlier)
      for (int c = tid; c < nm0; c += NT) {
        float4 m = s_mbox[c];
        int mcls = (int)(s_cc[c] >> 14);
        float aB = (m.z - m.x) * (m.w - m.y);
        for (int b2 = 0; b2 < BATCH; ++b2) {
          float qx1 = s_batch[b2][0], qy1 = s_batch[b2][1];
          if (fabsf(m.x - qx1) < 60.0f && fabsf(m.y - qy1) < 60.0f &&
              mcls == (int)s_batch[b2][5]) {
            float qx2 = s_batch[b2][2], qy2 = s_batch[b2][3];
            float xx1 = fmaxf(m.x, qx1), yy1 = fmaxf(m.y, qy1);
            float xx2 = fminf(m.z, qx2), yy2 = fminf(m.w, qy2);
            float iw = fmaxf(xx2 - xx1, 0.0f), ih = fmaxf(yy2 - yy1, 0.0f);
            float inter = iw * ih;
            float aA = (qx2 - qx1) * (qy2 - qy1);
            float uni = aA + aB - inter;
            if (uni > 0.0f && inter / uni > IOU_THR) {
              int pos = atomicAdd(&s_ccnt[b2], 1);
              if (pos < KCAND) ((unsigned short*)&s_cand4[b2])[pos] = (unsigned short)c;
            }
          }
        }
      }
    }
    // ---- phase 1.5: within-batch pairwise exact-IoU masks (j < b) ----
    #pragma unroll
    for (int q = 0; q < 4; ++q) {
      int p = tid + q * NT;
      int bb2 = p >> 6, jj = p & 63;
      if (jj < bb2) {
        unsigned gb = s_bgate[bb2], gj = s_bgate[jj];
        unsigned dx = __usad(gb >> 16, gj >> 16, 0u);
        unsigned dy = __usad(gb & 0xFFFFu, gj & 0xFFFFu, 0u);
        if (dx <= 60u && dy <= 60u) {
          float ax1 = s_batch[bb2][0], ay1 = s_batch[bb2][1];
          float ax2 = s_batch[bb2][2], ay2 = s_batch[bb2][3];
          float jx1 = s_batch[jj][0], jy1 = s_batch[jj][1];
          float jx2 = s_batch[jj][2], jy2 = s_batch[jj][3];
          float xx1 = fmaxf(ax1, jx1), yy1 = fmaxf(ay1, jy1);
          float xx2 = fminf(ax2, jx2), yy2 = fminf(ay2, jy2);
          float iw = fmaxf(xx2 - xx1, 0.0f), ih = fmaxf(yy2 - yy1, 0.0f);
          float inter = iw * ih;
          float aA = (ax2 - ax1) * (ay2 - ay1);
          float aB = (jx2 - jx1) * (jy2 - jy1);
          float uni = aA + aB - inter;
          if (uni > 0.0f && inter / uni > IOU_THR)
            atomicOr(&s_pm[bb2], 1ull << jj);
        }
      }
    }
    __syncthreads();

    // ---- resolution: wave 0, flagged boxes only; dirty bits in VGPRs ----
    if (tid < 64) {
      const int lane = tid;
      float4 qa = *(const float4*)&s_batch[lane][0];
      float2 qb = *(const float2*)&s_batch[lane][4];
      float p0 = qa.x, p1 = qa.y, p2 = qa.z, p3 = qa.w, p4 = qb.x, p5 = qb.y;
      int   cc_l = s_ccnt[lane];
      uint4 cp_l = s_cand4[lane];
      unsigned long long pm_l = s_pm[lane];
      int pml_lo = (int)(unsigned)pm_l, pml_hi = (int)(unsigned)(pm_l >> 32);
      // prefetch first candidate's state (parallel; exact: pulls are dirty-filtered)
      int c0 = (int)(cp_l.x & 0xFFFFu);
      float4 wp0 = make_float4(0.f, 0.f, 0.f, 0.f);
      float ssp0 = 1.0f; int ctp0 = 0;
      if (cc_l > 0) { wp0 = g_wsum[c0]; ssp0 = s_ssum[c0]; ctp0 = (int)s_cc[c0]; }

      unsigned dlo = 0u, dhi = 0u;   // dirty bits for clusters [lane*64, lane*64+64)

      unsigned long long anycand = __ballot(cc_l > 0);
      unsigned long long OVF = __ballot(cc_l > KCAND);
      unsigned long long F = __ballot(cc_l > 0 || pm_l != 0ull);
      int rs = BATCH;
      if (OVF) rs = (int)__builtin_ctzll(OVF);
      unsigned long long lowrs = (rs >= 64) ? ~0ull : ((1ull << rs) - 1ull);
      unsigned long long rem = F & lowrs;
      unsigned long long NEWM = ~F & lowrs;
      unsigned long long consumed = 0ull;

      int nmod = 0;
      int e_valid = 0, e_idx = INF, e_ct = 0, e_origbb = -1;
      float e_cls = -1.0f;
      float e_m0=0,e_m1=0,e_m2=0,e_m3=0, e_w0=0,e_w1=0,e_w2=0,e_w3=0, e_ss=0;

      while (rem) {
        int b = (int)__builtin_ctzll(rem);
        rem &= rem - 1ull;
        float bx1 = rl_f(p0, b), by1 = rl_f(p1, b);
        float bx2 = rl_f(p2, b), by2 = rl_f(p3, b);
        float sc  = rl_f(p4, b), lbf = rl_f(p5, b);

        int v = INF;
        // (a) recheck modified entries vs CURRENT state
        if (e_valid && e_cls == lbf &&
            fabsf(e_m0 - bx1) < 60.0f && fabsf(e_m1 - by1) < 60.0f) {
          float xx1 = fmaxf(e_m0, bx1), yy1 = fmaxf(e_m1, by1);
          float xx2 = fminf(e_m2, bx2), yy2 = fminf(e_m3, by2);
          float iw = fmaxf(xx2 - xx1, 0.0f), ih = fmaxf(yy2 - yy1, 0.0f);
          float inter = iw * ih;
          float aA = (bx2 - bx1) * (by2 - by1);
          float aB = (e_m2 - e_m0) * (e_m3 - e_m1);
          float uni = aA + aB - inter;
          if (uni > 0.0f && inter / uni > IOU_THR) v = e_idx;
        }
        // (b) clean pre-batch candidates (dirty-filtered via bpermute, full convergence)
        if ((anycand >> b) & 1ull) {
          int cc = rl_i(cc_l, b);
          unsigned w0 = (unsigned)rl_i((int)cp_l.x, b);
          unsigned w1 = (unsigned)rl_i((int)cp_l.y, b);
          unsigned w2 = (unsigned)rl_i((int)cp_l.z, b);
          unsigned w3 = (unsigned)rl_i((int)cp_l.w, b);
          unsigned w = (lane >= 6) ? w3 : (lane >= 4) ? w2 : (lane >= 2) ? w1 : w0;
          int ci = (int)((w >> ((lane & 1) * 16)) & 0xFFFFu);
          int widx = (ci >> 6) & 63;            // mask guards stale/garbage slots
          unsigned dl = (unsigned)__builtin_amdgcn_ds_bpermute(widx << 2, (int)dlo);
          unsigned dh = (unsigned)__builtin_amdgcn_ds_bpermute(widx << 2, (int)dhi);
          unsigned word = (ci & 32) ? dh : dl;
          if (lane < cc && !((word >> (ci & 31)) & 1u)) v = min(v, ci);
        }
        unsigned long long ball = __ballot(v != INF);
        int mn = INF;
        if (ball != 0ull) {
          if (__popcll(ball) == 1) {
            mn = rl_i(v, (int)__builtin_ctzll(ball));
          } else {
            int t = v;
            for (int o = 32; o; o >>= 1) t = min(t, __shfl_xor(t, o));
            mn = t;
          }
        }
        // (c) within-batch singleton pair candidate
        unsigned long long pc =
            (((unsigned long long)(unsigned)rl_i(pml_hi, b)) << 32) |
            (unsigned long long)(unsigned)rl_i(pml_lo, b);
        pc &= ~F & ~consumed;
        int pj = 64, pairidx = INF;
        if (pc) {
          pj = (int)__builtin_ctzll(pc);
          pairidx = nm0 + (int)__builtin_popcountll(NEWM & ((1ull << pj) - 1ull));
        }
        if (pairidx < mn) mn = pairidx;

        if (mn == INF) {
          int nidx = nm0 + (int)__builtin_popcountll(NEWM & ((1ull << b) - 1ull));
          NEWM |= 1ull << b;
          if (lane == nmod) {
            e_valid = 1; e_idx = nidx; e_cls = lbf; e_origbb = -1;
            e_w0 = sc * bx1; e_w1 = sc * by1; e_w2 = sc * bx2; e_w3 = sc * by2;
            e_ss = sc; e_ct = 1;
            e_m0 = e_w0 / e_ss; e_m1 = e_w1 / e_ss; e_m2 = e_w2 / e_ss; e_m3 = e_w3 / e_ss;
          }
          nmod++;
        } else {
          bool mine = e_valid && (e_idx == mn);
          unsigned long long mb = __ballot(mine);
          int owner;
          if (mb != 0ull) {
            owner = (int)__builtin_ctzll(mb);
            if (mine) {
              e_w0 += sc * bx1; e_w1 += sc * by1; e_w2 += sc * bx2; e_w3 += sc * by2;
              e_ss += sc; e_ct += 1;
              e_m0 = e_w0 / e_ss; e_m1 = e_w1 / e_ss; e_m2 = e_w2 / e_ss; e_m3 = e_w3 / e_ss;
            }
          } else if (mn < nm0) {
            owner = nmod;
            int rc0 = rl_i(c0, b);   // uniform: prefetched cand0 of box b
            if (lane == nmod) {      // pull clean cluster
              float w0, w1, w2, w3, ss; int ctp;
              if (mn == rc0) {
                w0 = rl_f(wp0.x, b); w1 = rl_f(wp0.y, b);
                w2 = rl_f(wp0.z, b); w3 = rl_f(wp0.w, b);
                ss = rl_f(ssp0, b);  ctp = rl_i(ctp0, b);
              } else {
                float4 w = g_wsum[mn];
                w0 = w.x; w1 = w.y; w2 = w.z; w3 = w.w;
                ss = s_ssum[mn]; ctp = (int)s_cc[mn];
              }
              e_valid = 1; e_idx = mn; e_cls = lbf;
              e_origbb = ((int)(w0 / ss)) >> 8;     // == bin(old m.x), bitwise-same divide
              e_w0 = w0 + sc * bx1; e_w1 = w1 + sc * by1;
              e_w2 = w2 + sc * bx2; e_w3 = w3 + sc * by2;
              e_ss = ss + sc; e_ct = (ctp & 0x3FFF) + 1;
              e_m0 = e_w0 / e_ss; e_m1 = e_w1 / e_ss; e_m2 = e_w2 / e_ss; e_m3 = e_w3 / e_ss;
            }
            // mark dirty (register-resident; mn uniform)
            if (lane == ((mn >> 6) & 63)) {
              if (mn & 32) dhi |= 1u << (mn & 31); else dlo |= 1u << (mn & 31);
            }
            nmod++;
          } else {
            owner = nmod;                           // pull unflagged singleton pj
            consumed |= 1ull << pj;
            if (lane == nmod) {
              float jx1 = rl_f(p0, pj), jy1 = rl_f(p1, pj);
              float jx2 = rl_f(p2, pj), jy2 = rl_f(p3, pj);
              float jsc = rl_f(p4, pj);
              e_valid = 1; e_idx = mn; e_cls = lbf; e_origbb = -1;
              e_w0 = jsc * jx1 + sc * bx1; e_w1 = jsc * jy1 + sc * by1;
              e_w2 = jsc * jx2 + sc * bx2; e_w3 = jsc * jy2 + sc * by2;
              e_ss = jsc + sc; e_ct = 2;
              e_m0 = e_w0 / e_ss; e_m1 = e_w1 / e_ss; e_m2 = e_w2 / e_ss; e_m3 = e_w3 / e_ss;
            }
            nmod++;
          }
          // detection: did this merge capture a later unflagged box?
          float nx1 = rl_f(e_m0, owner), ny1 = rl_f(e_m1, owner);
          float nx2 = rl_f(e_m2, owner), ny2 = rl_f(e_m3, owner);
          bool dp = false;
          if (p5 == lbf) {
            float xx1 = fmaxf(nx1, p0), yy1 = fmaxf(ny1, p1);
            float xx2 = fminf(nx2, p2), yy2 = fminf(ny2, p3);
            float iw = fmaxf(xx2 - xx1, 0.0f), ih = fmaxf(yy2 - yy1, 0.0f);
            float inter = iw * ih;
            float aA = (p2 - p0) * (p3 - p1);
            float aB = (nx2 - nx1) * (ny2 - ny1);
            float uni = aA + aB - inter;
            dp = (uni > 0.0f) && (inter / uni > IOU_THR);
          }
          unsigned long long det = __ballot(dp);
          unsigned long long himask = (b >= 63) ? 0ull : (~0ull << (b + 1));
          det &= ~F & ~consumed & lowrs & himask;
          if (det) { F |= det; rem |= det; NEWM &= ~det; }
        }
      }

      // writeback modified entries (+ bucket/gate invariant maintenance)
      if (e_valid) {
        s_mbox[e_idx] = make_float4(e_m0, e_m1, e_m2, e_m3);
        g_wsum[e_idx] = make_float4(e_w0, e_w1, e_w2, e_w3);
        s_ssum[e_idx] = e_ss;
        s_cc[e_idx] = (unsigned short)(e_ct | (((int)e_cls) << 14));
        s_gate32[e_idx] = ((unsigned)(int)e_m0 << 16) | (unsigned)(int)e_m1;
        int nb = ((int)e_m0) >> 8;
        if (nb < 0) nb = 0; if (nb > NBINS - 1) nb = NBINS - 1;
        if (nb != e_origbb) {
          int bk = ((int)e_cls) * NBINS + nb;
          int p = atomicAdd(&s_bktlen[bk], 1);
          if (p < BCAP) s_bkt[bk][p] = (unsigned short)e_idx; else s_ovf = 1;
        }
      }
      // bulk-materialize untouched singletons
      {
        unsigned long long selfbit = 1ull << lane;
        if (NEWM & ~F & ~consumed & selfbit) {
          int idx = nm0 + (int)__builtin_popcountll(NEWM & (selfbit - 1ull));
          float w0 = p4 * p0, w1 = p4 * p1, w2 = p4 * p2, w3 = p4 * p3;
          float m0 = w0 / p4, m1 = w1 / p4, m2 = w2 / p4, m3 = w3 / p4;
          g_wsum[idx] = make_float4(w0, w1, w2, w3);
          s_ssum[idx] = p4;
          s_cc[idx] = (unsigned short)(1 | (((int)p5) << 14));
          s_mbox[idx] = make_float4(m0, m1, m2, m3);
          s_gate32[idx] = ((unsigned)(int)m0 << 16) | (unsigned)(int)m1;
          int nb = ((int)m0) >> 8;
          if (nb < 0) nb = 0; if (nb > NBINS - 1) nb = NBINS - 1;
          int bk = ((int)p5) * NBINS + nb;
          int p = atomicAdd(&s_bktlen[bk], 1);
          if (p < BCAP) s_bkt[bk][p] = (unsigned short)idx; else s_ovf = 1;
        }
      }
      if (lane == 0) {
        s_num = nm0 + (int)__builtin_popcountll(NEWM);
        s_resume = rs;
      }
    }
    __syncthreads();

    // ---- exact serial fallback (candidate overflow; rare) ----
    int rs2 = s_resume;
    if (rs2 < BATCH) {
      for (int i = rs2; i < BATCH; ++i) {
        float bx1 = s_batch[i][0], by1 = s_batch[i][1];
        float bx2 = s_batch[i][2], by2 = s_batch[i][3];
        float sc  = s_batch[i][4];
        int lb = (int)s_batch[i][5];
        int nm = s_num;
        float aA = (bx2 - bx1) * (by2 - by1);
        int mymin = INF;
        for (int c = tid; c < nm; c += NT) {
          float4 m = s_mbox[c];
          if (fabsf(m.x - bx1) < 60.0f && fabsf(m.y - by1) < 60.0f &&
              (int)(s_cc[c] >> 14) == lb) {
            float xx1 = fmaxf(m.x, bx1), yy1 = fmaxf(m.y, by1);
            float xx2 = fminf(m.z, bx2), yy2 = fminf(m.w, by2);
            float iw = fmaxf(xx2 - xx1, 0.0f), ih = fmaxf(yy2 - yy1, 0.0f);
            float inter = iw * ih;
            float aB = (m.z - m.x) * (m.w - m.y);
            float uni = aA + aB - inter;
            if (uni > 0.0f && inter / uni > IOU_THR) mymin = min(mymin, c);
          }
        }
        if (mymin != INF) atomicMin(&s_min[i & 1], mymin);
        __syncthreads();
        int mn = s_min[i & 1];
        if (tid == 0) {
          s_min[(i + 1) & 1] = INF;
          bool has = (mn != INF);
          int idx = has ? mn : nm;
          float w0, w1, w2, w3, ss; int ct, ob = -1;
          if (has) {
            float4 w = g_wsum[idx];
            w0 = w.x; w1 = w.y; w2 = w.z; w3 = w.w;
            ss = s_ssum[idx]; ct = (int)(s_cc[idx] & 0x3FFF);
            ob = ((int)s_mbox[idx].x) >> 8;
          } else { w0 = w1 = w2 = w3 = 0.0f; ss = 0.0f; ct = 0; }
          w0 += sc * bx1; w1 += sc * by1; w2 += sc * bx2; w3 += sc * by2;
          ss += sc; ct += 1;
          float m0 = w0 / ss, m1 = w1 / ss, m2 = w2 / ss, m3 = w3 / ss;
          g_wsum[idx] = make_float4(w0, w1, w2, w3);
          s_ssum[idx] = ss;
          s_cc[idx] = (unsigned short)(ct | (lb << 14));
          s_mbox[idx] = make_float4(m0, m1, m2, m3);
          s_gate32[idx] = ((unsigned)(int)m0 << 16) | (unsigned)(int)m1;
          int nb = ((int)m0) >> 8;
          if (nb < 0) nb = 0; if (nb > NBINS - 1) nb = NBINS - 1;
          if (nb != ob) {
            int bk = lb * NBINS + nb;
            int p = atomicAdd(&s_bktlen[bk], 1);
            if (p < BCAP) s_bkt[bk][p] = (unsigned short)idx; else s_ovf = 1;
          }
          if (!has) s_num = nm + 1;
        }
        __syncthreads();
      }
      if (tid == 0) { s_min[0] = INF; s_min[1] = INF; }
    }
  }

  // ================= scoring + sort keys (keys alias s_mbox) =================
  __syncthreads();
  unsigned long long* s_keys = (unsigned long long*)s_mbox;
  int num = s_num;
  for (int j = tid; j < N; j += NT) {
    unsigned int lo = ~(unsigned int)j;              // lower index wins ties
    unsigned long long key;
    if (j < num) {
      float ct = (float)(s_cc[j] & 0x3FFF);
      float sco = s_ssum[j] / fmaxf(ct, 1.0f);       // bitwise == reference score
      unsigned int bb = __float_as_uint(sco) | 0x80000000u;
      key = ((unsigned long long)bb << 32) | lo;
    } else {
      key = (0x407FFFFFull << 32) | lo;              // mapped bits of -1.0f sort key
    }
    s_keys[j] = key;
  }
  __syncthreads();

  // ---- bitonic sort, descending, 4096 u64 keys ----
  for (int k = 2; k <= N; k <<= 1) {
    for (int j = k >> 1; j > 0; j >>= 1) {
      #pragma unroll
      for (int w = 0; w < N / NT; ++w) {
        int a0 = tid + (w << 10);
        int l = a0 ^ j;
        if (l > a0) {
          unsigned long long a = s_keys[a0], bq = s_keys[l];
          bool desc = ((a0 & k) == 0);
          bool sw = desc ? (a < bq) : (a > bq);
          if (sw) { s_keys[a0] = bq; s_keys[l] = a; }
        }
      }
      __syncthreads();
    }
  }

  // ---- emit top-1000 rows (box = g_wsum/ssum, bitwise == stored mbox) ----
  if (tid < 1000) {
    unsigned long long key = s_keys[tid];
    unsigned int hi = (unsigned int)(key >> 32);
    float* o = out + (size_t)tid * 6;
    if (hi & 0x80000000u) {
      int j = (int)(~(unsigned int)key);
      float4 w = g_wsum[j];
      float ss = s_ssum[j];
      o[0] = w.x / ss; o[1] = w.y / ss; o[2] = w.z / ss; o[3] = w.w / ss;
      o[4] = __uint_as_float(hi & 0x7FFFFFFFu);
      o[5] = (float)(s_cc[j] >> 14);
    } else {
      o[0] = 0.0f; o[1] = 0.0f; o[2] = 0.0f;
      o[3] = 0.0f; o[4] = 0.0f; o[5] = 0.0f;
    }
  }
}

extern "C" void kernel_launch(void* const* d_in, const int* in_sizes, int n_in,
                              void* d_out, int out_size, void* d_ws, size_t ws_size,
                              hipStream_t stream) {
  const float* boxes = (const float*)d_in[0];
  const float* offs  = (const float*)d_in[1];
  float* out = (float*)d_out;
  hipLaunchKernelGGL(wbf_kernel, dim3(1), dim3(NT), 0, stream, boxes, offs, out);
}

// Round 9
// 305.813 us; speedup vs baseline: 1.0655x; 1.0655x over previous
//
#include <hip/hip_runtime.h>

#define N 4096
#define NT 1024
#define BATCH 64
#define KCAND 8
#define IOU_THR 0.55f
#define INF 0x7fffffff
#define NBINS 14
#define NBKT 42     // 3 classes * 14 x-bins of 256px
#define BCAP 320

__device__ float4 g_wsum[N];   // weighted sums; always written before read per launch

__device__ __forceinline__ float rl_f(float v, int lane) {
  return __int_as_float(__builtin_amdgcn_readlane(__float_as_int(v), lane));
}
__device__ __forceinline__ int rl_i(int v, int lane) {
  return __builtin_amdgcn_readlane(v, lane);
}

__global__ __launch_bounds__(NT) void wbf_kernel(
    const float* __restrict__ boxes,   // [16,256,6]
    const float* __restrict__ offs,    // [16,2]
    float* __restrict__ out)           // [1000,6]
{
  // ---- LDS ~121.8 KB (limit 160 KB) ----
  __shared__ float4 s_mbox[N];                   // 64 KB (sort keys alias later)
  __shared__ float  s_ssum[N];                   // 16 KB
  __shared__ unsigned short s_cc[N];             //  8 KB  cnt | cls<<14
  __shared__ unsigned short s_bkt[NBKT][BCAP];   // 26.25 KB cluster-index buckets
  __shared__ int s_bktlen[NBKT];
  __shared__ unsigned long long s_dirty[64];
  __shared__ uint4 s_cand4[BATCH];               // 8 x u16 candidates per box
  __shared__ int   s_ccnt[BATCH];
  __shared__ float s_batch[BATCH][6];
  __shared__ unsigned s_bgate[BATCH];            // (cls<<12|x)<<16 | y  (phase 1.5)
  __shared__ unsigned long long s_pm[BATCH];
  __shared__ unsigned s_cbm[128];                // 4096-bit candidate-cluster bitmap
  __shared__ int s_min[2];
  __shared__ int s_num, s_resume, s_ovf, s_coll;

  const int tid = threadIdx.x;

  if (tid < 64) s_dirty[tid] = 0ull;
  if (tid < NBKT) s_bktlen[tid] = 0;
  if (tid == 0) { s_num = 0; s_resume = BATCH; s_ovf = 0; s_min[0] = INF; s_min[1] = INF; }

  // ================= batched WBF scan =================
  for (int t0 = 0; t0 < N; t0 += BATCH) {
    // ---- stage batch boxes; clear counters/masks/bitmap ----
    if (tid < BATCH * 6) {
      int b = tid / 6, f = tid % 6;
      int gi = t0 + b;
      float v = boxes[(size_t)gi * 6 + f];
      if (f < 4) v += offs[((gi >> 8) << 1) + (f & 1)];
      s_batch[b][f] = v;
    } else if (tid < BATCH * 7) {
      s_ccnt[tid - BATCH * 6] = 0;
    } else if (tid < BATCH * 8) {
      s_pm[tid - BATCH * 7] = 0ull;
    } else if (tid < BATCH * 8 + 128) {
      s_cbm[tid - BATCH * 8] = 0u;
    } else if (tid == BATCH * 8 + 128) {
      s_coll = 0;
    }
    __syncthreads();

    int nm0 = s_num;
    if (tid < BATCH) {
      int qx = (int)s_batch[tid][0];
      int qy = (int)s_batch[tid][1];
      int lb = (int)s_batch[tid][5];
      s_bgate[tid] = ((unsigned)((lb << 12) | qx) << 16) | (unsigned)qy;
    }
    __syncthreads();

    // ---- phase 1: candidates vs clean pre-batch clusters (bucketed) ----
    int use_linear = s_ovf;
    if (!use_linear) {
      int b = tid >> 4, sl = tid & 15;        // 16 threads per box
      float qx1 = s_batch[b][0], qy1 = s_batch[b][1];
      float qx2 = s_batch[b][2], qy2 = s_batch[b][3];
      int cls = (int)s_batch[b][5];
      float aA = (qx2 - qx1) * (qy2 - qy1);
      int bb = ((int)qx1) >> 8;
      int jlo = bb > 0 ? bb - 1 : 0;
      int jhi = bb < NBINS - 1 ? bb + 1 : NBINS - 1;
      for (int j = jlo; j <= jhi; ++j) {
        int bk = cls * NBINS + j;
        int len = s_bktlen[bk]; if (len > BCAP) len = BCAP;
        for (int e = sl; e < len; e += 16) {
          int c = (int)s_bkt[bk][e];
          float4 m = s_mbox[c];
          if (fabsf(m.x - qx1) < 60.0f && fabsf(m.y - qy1) < 60.0f) {
            float xx1 = fmaxf(m.x, qx1), yy1 = fmaxf(m.y, qy1);
            float xx2 = fminf(m.z, qx2), yy2 = fminf(m.w, qy2);
            float iw = fmaxf(xx2 - xx1, 0.0f), ih = fmaxf(yy2 - yy1, 0.0f);
            float inter = iw * ih;
            float aB = (m.z - m.x) * (m.w - m.y);
            float uni = aA + aB - inter;
            if (uni > 0.0f && inter / uni > IOU_THR) {
              int pos = atomicAdd(&s_ccnt[b], 1);
              if (pos < KCAND) ((unsigned short*)&s_cand4[b])[pos] = (unsigned short)c;
              unsigned bit = 1u << (c & 31);
              if (atomicOr(&s_cbm[c >> 5], bit) & bit) s_coll = 1;
            }
          }
        }
      }
    } else {
      // exact linear fallback (bucket overflow happened earlier)
      for (int c = tid; c < nm0; c += NT) {
        float4 m = s_mbox[c];
        int mcls = (int)(s_cc[c] >> 14);
        float aB = (m.z - m.x) * (m.w - m.y);
        for (int b2 = 0; b2 < BATCH; ++b2) {
          float qx1 = s_batch[b2][0], qy1 = s_batch[b2][1];
          if (fabsf(m.x - qx1) < 60.0f && fabsf(m.y - qy1) < 60.0f &&
              mcls == (int)s_batch[b2][5]) {
            float qx2 = s_batch[b2][2], qy2 = s_batch[b2][3];
            float xx1 = fmaxf(m.x, qx1), yy1 = fmaxf(m.y, qy1);
            float xx2 = fminf(m.z, qx2), yy2 = fminf(m.w, qy2);
            float iw = fmaxf(xx2 - xx1, 0.0f), ih = fmaxf(yy2 - yy1, 0.0f);
            float inter = iw * ih;
            float aA = (qx2 - qx1) * (qy2 - qy1);
            float uni = aA + aB - inter;
            if (uni > 0.0f && inter / uni > IOU_THR) {
              int pos = atomicAdd(&s_ccnt[b2], 1);
              if (pos < KCAND) ((unsigned short*)&s_cand4[b2])[pos] = (unsigned short)c;
              unsigned bit = 1u << (c & 31);
              if (atomicOr(&s_cbm[c >> 5], bit) & bit) s_coll = 1;
            }
          }
        }
      }
    }
    // ---- phase 1.5: within-batch pairwise exact-IoU masks (j < b) ----
    #pragma unroll
    for (int q = 0; q < 4; ++q) {
      int p = tid + q * NT;
      int bb2 = p >> 6, jj = p & 63;
      if (jj < bb2) {
        unsigned gb = s_bgate[bb2], gj = s_bgate[jj];
        unsigned dx = __usad(gb >> 16, gj >> 16, 0u);
        unsigned dy = __usad(gb & 0xFFFFu, gj & 0xFFFFu, 0u);
        if (dx <= 60u && dy <= 60u) {
          float ax1 = s_batch[bb2][0], ay1 = s_batch[bb2][1];
          float ax2 = s_batch[bb2][2], ay2 = s_batch[bb2][3];
          float jx1 = s_batch[jj][0], jy1 = s_batch[jj][1];
          float jx2 = s_batch[jj][2], jy2 = s_batch[jj][3];
          float xx1 = fmaxf(ax1, jx1), yy1 = fmaxf(ay1, jy1);
          float xx2 = fminf(ax2, jx2), yy2 = fminf(ay2, jy2);
          float iw = fmaxf(xx2 - xx1, 0.0f), ih = fmaxf(yy2 - yy1, 0.0f);
          float inter = iw * ih;
          float aA = (ax2 - ax1) * (ay2 - ay1);
          float aB = (jx2 - jx1) * (jy2 - jy1);
          float uni = aA + aB - inter;
          if (uni > 0.0f && inter / uni > IOU_THR)
            atomicOr(&s_pm[bb2], 1ull << jj);
        }
      }
    }
    __syncthreads();

    // ---- resolution: wave 0 ----
    if (tid < 64) {
      const int lane = tid;
      float p0 = s_batch[lane][0], p1 = s_batch[lane][1], p2 = s_batch[lane][2];
      float p3 = s_batch[lane][3], p4 = s_batch[lane][4], p5 = s_batch[lane][5];
      int   cc_l = s_ccnt[lane];
      uint4 cp_l = s_cand4[lane];
      unsigned long long pm_l = s_pm[lane];

      unsigned long long anycand = __ballot(cc_l > 0);
      unsigned long long OVF = __ballot(cc_l > KCAND);
      unsigned long long PAIRS = __ballot(pm_l != 0ull);
      unsigned long long F = anycand | PAIRS;
      int rs = BATCH;
      if (OVF) rs = (int)__builtin_ctzll(OVF);
      unsigned long long lowrs = (rs >= 64) ? ~0ull : ((1ull << rs) - 1ull);
      unsigned long long rem = F & lowrs;
      unsigned long long NEWM = ~F & lowrs;
      unsigned long long consumed = 0ull;

      int coll = s_coll;
      bool fast = (OVF == 0ull) && (PAIRS == 0ull) && (coll == 0);

      int nmod = 0;
      int e_valid = 0, e_idx = INF, e_ct = 0, e_origbb = -1;
      float e_cls = -1.0f;
      float e_m0=0,e_m1=0,e_m2=0,e_m3=0, e_w0=0,e_w1=0,e_w2=0,e_w3=0, e_ss=0;

      // ======== FAST PATH: all flagged boxes merge disjoint clean clusters ========
      if (fast) {
        bool merging = (cc_l > 0);
        int mnl = INF;
        const unsigned short* cl = (const unsigned short*)&cp_l;
        #pragma unroll
        for (int k = 0; k < KCAND; ++k)
          if (k < cc_l) mnl = min(mnl, (int)cl[k]);
        if (merging) {
          float4 w = g_wsum[mnl];
          float ss = s_ssum[mnl]; int ctp = (int)s_cc[mnl];
          e_valid = 1; e_idx = mnl; e_cls = p5;
          e_origbb = ((int)(w.x / ss)) >> 8;     // == bin(old m.x), bitwise-same divide
          e_w0 = w.x + p4 * p0; e_w1 = w.y + p4 * p1;
          e_w2 = w.z + p4 * p2; e_w3 = w.w + p4 * p3;
          e_ss = ss + p4; e_ct = (ctp & 0x3FFF) + 1;
          e_m0 = e_w0 / e_ss; e_m1 = e_w1 / e_ss; e_m2 = e_w2 / e_ss; e_m3 = e_w3 / e_ss;
        }
        // conservative capture check: each post-merge box vs all 64 raw boxes
        unsigned long long it = __ballot(merging);
        bool bad = false;
        while (it) {
          int o = (int)__builtin_ctzll(it); it &= it - 1ull;
          float nx1 = rl_f(e_m0, o), ny1 = rl_f(e_m1, o);
          float nx2 = rl_f(e_m2, o), ny2 = rl_f(e_m3, o);
          float ncls = rl_f(e_cls, o);
          bool hit = false;
          if (lane != o && p5 == ncls) {
            float xx1 = fmaxf(nx1, p0), yy1 = fmaxf(ny1, p1);
            float xx2 = fminf(nx2, p2), yy2 = fminf(ny2, p3);
            float iw = fmaxf(xx2 - xx1, 0.0f), ih = fmaxf(yy2 - yy1, 0.0f);
            float inter = iw * ih;
            float aA = (p2 - p0) * (p3 - p1);
            float aB = (nx2 - nx1) * (ny2 - ny1);
            float uni = aA + aB - inter;
            hit = (uni > 0.0f) && (inter / uni > IOU_THR);
          }
          if (__ballot(hit) != 0ull) { bad = true; break; }
        }
        if (bad) {   // discard; state untouched -> exact serial path
          fast = false;
          e_valid = 0; e_idx = INF; e_ct = 0; e_origbb = -1; e_cls = -1.0f;
          e_m0=e_m1=e_m2=e_m3=e_w0=e_w1=e_w2=e_w3=e_ss=0.0f;
        }
      }

      // ======== SERIAL PATH (exact, unchanged from R7) ========
      if (!fast) {
        int pml_lo = (int)(unsigned)pm_l, pml_hi = (int)(unsigned)(pm_l >> 32);
        int c0 = (int)(cp_l.x & 0xFFFFu);
        float4 wp0 = make_float4(0.f, 0.f, 0.f, 0.f);
        float ssp0 = 1.0f; int ctp0 = 0;
        if (cc_l > 0) { wp0 = g_wsum[c0]; ssp0 = s_ssum[c0]; ctp0 = (int)s_cc[c0]; }

        while (rem) {
          int b = (int)__builtin_ctzll(rem);
          rem &= rem - 1ull;
          float bx1 = rl_f(p0, b), by1 = rl_f(p1, b);
          float bx2 = rl_f(p2, b), by2 = rl_f(p3, b);
          float sc  = rl_f(p4, b), lbf = rl_f(p5, b);

          int v = INF;
          // (a) recheck modified entries vs CURRENT state
          if (e_valid && e_cls == lbf &&
              fabsf(e_m0 - bx1) < 60.0f && fabsf(e_m1 - by1) < 60.0f) {
            float xx1 = fmaxf(e_m0, bx1), yy1 = fmaxf(e_m1, by1);
            float xx2 = fminf(e_m2, bx2), yy2 = fminf(e_m3, by2);
            float iw = fmaxf(xx2 - xx1, 0.0f), ih = fmaxf(yy2 - yy1, 0.0f);
            float inter = iw * ih;
            float aA = (bx2 - bx1) * (by2 - by1);
            float aB = (e_m2 - e_m0) * (e_m3 - e_m1);
            float uni = aA + aB - inter;
            if (uni > 0.0f && inter / uni > IOU_THR) v = e_idx;
          }
          // (b) clean pre-batch candidates (dirty-filtered)
          if ((anycand >> b) & 1ull) {
            int cc = rl_i(cc_l, b);
            unsigned w0 = (unsigned)rl_i((int)cp_l.x, b);
            unsigned w1 = (unsigned)rl_i((int)cp_l.y, b);
            unsigned w2 = (unsigned)rl_i((int)cp_l.z, b);
            unsigned w3 = (unsigned)rl_i((int)cp_l.w, b);
            if (lane < cc) {
              unsigned w = (lane >= 6) ? w3 : (lane >= 4) ? w2 : (lane >= 2) ? w1 : w0;
              int ci = (int)((w >> ((lane & 1) * 16)) & 0xFFFFu);
              if (!((s_dirty[ci >> 6] >> (ci & 63)) & 1ull)) v = min(v, ci);
            }
          }
          unsigned long long ball = __ballot(v != INF);
          int mn = INF;
          if (ball != 0ull) {
            if (__popcll(ball) == 1) {
              mn = rl_i(v, (int)__builtin_ctzll(ball));
            } else {
              int t = v;
              for (int o = 32; o; o >>= 1) t = min(t, __shfl_xor(t, o));
              mn = t;
            }
          }
          // (c) within-batch singleton pair candidate
          unsigned long long pc =
              (((unsigned long long)(unsigned)rl_i(pml_hi, b)) << 32) |
              (unsigned long long)(unsigned)rl_i(pml_lo, b);
          pc &= ~F & ~consumed;
          int pj = 64, pairidx = INF;
          if (pc) {
            pj = (int)__builtin_ctzll(pc);
            pairidx = nm0 + (int)__builtin_popcountll(NEWM & ((1ull << pj) - 1ull));
          }
          if (pairidx < mn) mn = pairidx;

          if (mn == INF) {
            int nidx = nm0 + (int)__builtin_popcountll(NEWM & ((1ull << b) - 1ull));
            NEWM |= 1ull << b;
            if (lane == nmod) {
              e_valid = 1; e_idx = nidx; e_cls = lbf; e_origbb = -1;
              e_w0 = sc * bx1; e_w1 = sc * by1; e_w2 = sc * bx2; e_w3 = sc * by2;
              e_ss = sc; e_ct = 1;
              e_m0 = e_w0 / e_ss; e_m1 = e_w1 / e_ss; e_m2 = e_w2 / e_ss; e_m3 = e_w3 / e_ss;
            }
            nmod++;
          } else {
            bool mine = e_valid && (e_idx == mn);
            unsigned long long mb = __ballot(mine);
            int owner;
            if (mb != 0ull) {
              owner = (int)__builtin_ctzll(mb);
              if (mine) {
                e_w0 += sc * bx1; e_w1 += sc * by1; e_w2 += sc * bx2; e_w3 += sc * by2;
                e_ss += sc; e_ct += 1;
                e_m0 = e_w0 / e_ss; e_m1 = e_w1 / e_ss; e_m2 = e_w2 / e_ss; e_m3 = e_w3 / e_ss;
              }
            } else if (mn < nm0) {
              owner = nmod;
              int rc0 = rl_i(c0, b);
              if (lane == nmod) {
                float w0, w1, w2, w3, ss; int ctp;
                if (mn == rc0) {
                  w0 = rl_f(wp0.x, b); w1 = rl_f(wp0.y, b);
                  w2 = rl_f(wp0.z, b); w3 = rl_f(wp0.w, b);
                  ss = rl_f(ssp0, b);  ctp = rl_i(ctp0, b);
                } else {
                  float4 w = g_wsum[mn];
                  w0 = w.x; w1 = w.y; w2 = w.z; w3 = w.w;
                  ss = s_ssum[mn]; ctp = (int)s_cc[mn];
                }
                e_valid = 1; e_idx = mn; e_cls = lbf;
                e_origbb = ((int)(w0 / ss)) >> 8;
                e_w0 = w0 + sc * bx1; e_w1 = w1 + sc * by1;
                e_w2 = w2 + sc * bx2; e_w3 = w3 + sc * by2;
                e_ss = ss + sc; e_ct = (ctp & 0x3FFF) + 1;
                e_m0 = e_w0 / e_ss; e_m1 = e_w1 / e_ss; e_m2 = e_w2 / e_ss; e_m3 = e_w3 / e_ss;
                atomicOr(&s_dirty[mn >> 6], 1ull << (mn & 63));
              }
              nmod++;
            } else {
              owner = nmod;
              consumed |= 1ull << pj;
              if (lane == nmod) {
                float jx1 = rl_f(p0, pj), jy1 = rl_f(p1, pj);
                float jx2 = rl_f(p2, pj), jy2 = rl_f(p3, pj);
                float jsc = rl_f(p4, pj);
                e_valid = 1; e_idx = mn; e_cls = lbf; e_origbb = -1;
                e_w0 = jsc * jx1 + sc * bx1; e_w1 = jsc * jy1 + sc * by1;
                e_w2 = jsc * jx2 + sc * bx2; e_w3 = jsc * jy2 + sc * by2;
                e_ss = jsc + sc; e_ct = 2;
                e_m0 = e_w0 / e_ss; e_m1 = e_w1 / e_ss; e_m2 = e_w2 / e_ss; e_m3 = e_w3 / e_ss;
              }
              nmod++;
            }
            // detection: did this merge capture a later unflagged box?
            float nx1 = rl_f(e_m0, owner), ny1 = rl_f(e_m1, owner);
            float nx2 = rl_f(e_m2, owner), ny2 = rl_f(e_m3, owner);
            bool dp = false;
            if (p5 == rl_f(e_cls, owner)) {
              float xx1 = fmaxf(nx1, p0), yy1 = fmaxf(ny1, p1);
              float xx2 = fminf(nx2, p2), yy2 = fminf(ny2, p3);
              float iw = fmaxf(xx2 - xx1, 0.0f), ih = fmaxf(yy2 - yy1, 0.0f);
              float inter = iw * ih;
              float aA = (p2 - p0) * (p3 - p1);
              float aB = (nx2 - nx1) * (ny2 - ny1);
              float uni = aA + aB - inter;
              dp = (uni > 0.0f) && (inter / uni > IOU_THR);
            }
            unsigned long long det = __ballot(dp);
            unsigned long long himask = (b >= 63) ? 0ull : (~0ull << (b + 1));
            det &= ~F & ~consumed & lowrs & himask;
            if (det) { F |= det; rem |= det; NEWM &= ~det; }
          }
        }
      }

      // ======== shared writeback (both paths) ========
      if (e_valid) {
        s_mbox[e_idx] = make_float4(e_m0, e_m1, e_m2, e_m3);
        g_wsum[e_idx] = make_float4(e_w0, e_w1, e_w2, e_w3);
        s_ssum[e_idx] = e_ss;
        s_cc[e_idx] = (unsigned short)(e_ct | (((int)e_cls) << 14));
        int nb = ((int)e_m0) >> 8;
        if (nb < 0) nb = 0; if (nb > NBINS - 1) nb = NBINS - 1;
        if (nb != e_origbb) {
          int bk = ((int)e_cls) * NBINS + nb;
          int p = atomicAdd(&s_bktlen[bk], 1);
          if (p < BCAP) s_bkt[bk][p] = (unsigned short)e_idx; else s_ovf = 1;
        }
      }
      // bulk-materialize untouched singletons
      {
        unsigned long long selfbit = 1ull << lane;
        if (NEWM & ~F & ~consumed & selfbit) {
          int idx = nm0 + (int)__builtin_popcountll(NEWM & (selfbit - 1ull));
          float w0 = p4 * p0, w1 = p4 * p1, w2 = p4 * p2, w3 = p4 * p3;
          float m0 = w0 / p4, m1 = w1 / p4, m2 = w2 / p4, m3 = w3 / p4;
          g_wsum[idx] = make_float4(w0, w1, w2, w3);
          s_ssum[idx] = p4;
          s_cc[idx] = (unsigned short)(1 | (((int)p5) << 14));
          s_mbox[idx] = make_float4(m0, m1, m2, m3);
          int nb = ((int)m0) >> 8;
          if (nb < 0) nb = 0; if (nb > NBINS - 1) nb = NBINS - 1;
          int bk = ((int)p5) * NBINS + nb;
          int p = atomicAdd(&s_bktlen[bk], 1);
          if (p < BCAP) s_bkt[bk][p] = (unsigned short)idx; else s_ovf = 1;
        }
      }
      s_dirty[lane] = 0ull;
      if (lane == 0) {
        s_num = nm0 + (int)__builtin_popcountll(NEWM);
        s_resume = rs;
      }
    }
    __syncthreads();

    // ---- exact serial fallback (candidate overflow; rare) ----
    int rs2 = s_resume;
    if (rs2 < BATCH) {
      for (int i = rs2; i < BATCH; ++i) {
        float bx1 = s_batch[i][0], by1 = s_batch[i][1];
        float bx2 = s_batch[i][2], by2 = s_batch[i][3];
        float sc  = s_batch[i][4];
        int lb = (int)s_batch[i][5];
        int nm = s_num;
        float aA = (bx2 - bx1) * (by2 - by1);
        int mymin = INF;
        for (int c = tid; c < nm; c += NT) {
          float4 m = s_mbox[c];
          if (fabsf(m.x - bx1) < 60.0f && fabsf(m.y - by1) < 60.0f &&
              (int)(s_cc[c] >> 14) == lb) {
            float xx1 = fmaxf(m.x, bx1), yy1 = fmaxf(m.y, by1);
            float xx2 = fminf(m.z, bx2), yy2 = fminf(m.w, by2);
            float iw = fmaxf(xx2 - xx1, 0.0f), ih = fmaxf(yy2 - yy1, 0.0f);
            float inter = iw * ih;
            float aB = (m.z - m.x) * (m.w - m.y);
            float uni = aA + aB - inter;
            if (uni > 0.0f && inter / uni > IOU_THR) mymin = min(mymin, c);
          }
        }
        if (mymin != INF) atomicMin(&s_min[i & 1], mymin);
        __syncthreads();
        int mn = s_min[i & 1];
        if (tid == 0) {
          s_min[(i + 1) & 1] = INF;
          bool has = (mn != INF);
          int idx = has ? mn : nm;
          float w0, w1, w2, w3, ss; int ct, ob = -1;
          if (has) {
            float4 w = g_wsum[idx];
            w0 = w.x; w1 = w.y; w2 = w.z; w3 = w.w;
            ss = s_ssum[idx]; ct = (int)(s_cc[idx] & 0x3FFF);
            ob = ((int)s_mbox[idx].x) >> 8;
          } else { w0 = w1 = w2 = w3 = 0.0f; ss = 0.0f; ct = 0; }
          w0 += sc * bx1; w1 += sc * by1; w2 += sc * bx2; w3 += sc * by2;
          ss += sc; ct += 1;
          float m0 = w0 / ss, m1 = w1 / ss, m2 = w2 / ss, m3 = w3 / ss;
          g_wsum[idx] = make_float4(w0, w1, w2, w3);
          s_ssum[idx] = ss;
          s_cc[idx] = (unsigned short)(ct | (lb << 14));
          s_mbox[idx] = make_float4(m0, m1, m2, m3);
          int nb = ((int)m0) >> 8;
          if (nb < 0) nb = 0; if (nb > NBINS - 1) nb = NBINS - 1;
          if (nb != ob) {
            int bk = lb * NBINS + nb;
            int p = atomicAdd(&s_bktlen[bk], 1);
            if (p < BCAP) s_bkt[bk][p] = (unsigned short)idx; else s_ovf = 1;
          }
          if (!has) s_num = nm + 1;
        }
        __syncthreads();
      }
      if (tid == 0) { s_min[0] = INF; s_min[1] = INF; }
    }
  }

  // ================= scoring + sort keys (keys alias s_mbox) =================
  __syncthreads();
  unsigned long long* s_keys = (unsigned long long*)s_mbox;
  int num = s_num;
  for (int j = tid; j < N; j += NT) {
    unsigned int lo = ~(unsigned int)j;              // lower index wins ties
    unsigned long long key;
    if (j < num) {
      float ct = (float)(s_cc[j] & 0x3FFF);
      float sco = s_ssum[j] / fmaxf(ct, 1.0f);       // bitwise == reference score
      unsigned int bb = __float_as_uint(sco) | 0x80000000u;
      key = ((unsigned long long)bb << 32) | lo;
    } else {
      key = (0x407FFFFFull << 32) | lo;              // mapped bits of -1.0f sort key
    }
    s_keys[j] = key;
  }
  __syncthreads();

  // ---- bitonic sort, descending, 4096 u64 keys ----
  for (int k = 2; k <= N; k <<= 1) {
    for (int j = k >> 1; j > 0; j >>= 1) {
      #pragma unroll
      for (int w = 0; w < N / NT; ++w) {
        int a0 = tid + (w << 10);
        int l = a0 ^ j;
        if (l > a0) {
          unsigned long long a = s_keys[a0], bq = s_keys[l];
          bool desc = ((a0 & k) == 0);
          bool sw = desc ? (a < bq) : (a > bq);
          if (sw) { s_keys[a0] = bq; s_keys[l] = a; }
        }
      }
      __syncthreads();
    }
  }

  // ---- emit top-1000 rows (box = g_wsum/ssum, bitwise == stored mbox) ----
  if (tid < 1000) {
    unsigned long long key = s_keys[tid];
    unsigned int hi = (unsigned int)(key >> 32);
    float* o = out + (size_t)tid * 6;
    if (hi & 0x80000000u) {
      int j = (int)(~(unsigned int)key);
      float4 w = g_wsum[j];
      float ss = s_ssum[j];
      o[0] = w.x / ss; o[1] = w.y / ss; o[2] = w.z / ss; o[3] = w.w / ss;
      o[4] = __uint_as_float(hi & 0x7FFFFFFFu);
      o[5] = (float)(s_cc[j] >> 14);
    } else {
      o[0] = 0.0f; o[1] = 0.0f; o[2] = 0.0f;
      o[3] = 0.0f; o[4] = 0.0f; o[5] = 0.0f;
    }
  }
}

extern "C" void kernel_launch(void* const* d_in, const int* in_sizes, int n_in,
                              void* d_out, int out_size, void* d_ws, size_t ws_size,
                              hipStream_t stream) {
  const float* boxes = (const float*)d_in[0];
  const float* offs  = (const float*)d_in[1];
  float* out = (float*)d_out;
  hipLaunchKernelGGL(wbf_kernel, dim3(1), dim3(NT), 0, stream, boxes, offs, out);
}